// Round 3
// baseline (320.019 us; speedup 1.0000x reference)
//
#include <hip/hip_runtime.h>

// Problem constants (match reference)
#define BATCH    64
#define HEIGHT   512
#define WIDTH    512
#define CHAN     3
#define PATCH    8
#define NPH      64
#define NPW      64
#define NP_TOT   4096          // NPH*NPW
#define NUM_MASK 3072          // 0.75 * NP_TOT

#define PER_IMG4 (HEIGHT * WIDTH * CHAN / 4)   // 196608 float4 per image
#define PER_ROW4 (WIDTH * CHAN / 4)            // 384 float4 per row

#define BLOCKS_PER_IMG 48
#define CHUNK4 (PER_IMG4 / BLOCKS_PER_IMG)     // 4096 float4 per block
#define ITERS  (CHUNK4 / 256)                  // 16

// Single fused kernel: per-workgroup LDS patch-mask rebuild + masked copy.
// - LDS mask: 4096 bytes (one per patch of this image). Init to 1, then
//   scatter zeros from mask_indices (permutation prefix => distinct =>
//   byte stores race-free, LDS has byte-enables, no atomics needed).
// - Apply: one float4 per lane-iteration. A patch spans 24 contiguous
//   floats per row (6 float4), so each aligned float4 is within one patch.
//   Masked lanes skip the global load entirely (exec-masked dwordx4).
__global__ __launch_bounds__(256)
void rm_fused(const float4* __restrict__ in,
              float4* __restrict__ out,
              const int* __restrict__ mask_indices) {
    __shared__ unsigned char smask[NP_TOT];    // 4 KB

    const int b   = blockIdx.x / BLOCKS_PER_IMG;
    const int blk = blockIdx.x - b * BLOCKS_PER_IMG;
    const int t   = threadIdx.x;

    // 1) LDS mask := 1 (1024 dwords, 4 per thread)
    unsigned int* sm32 = (unsigned int*)smask;
#pragma unroll
    for (int i = 0; i < 4; ++i) sm32[i * 256 + t] = 0x01010101u;
    __syncthreads();

    // 2) scatter zeros (12 coalesced index loads per thread)
    const int* idx = mask_indices + b * NUM_MASK;
#pragma unroll
    for (int i = 0; i < 12; ++i) smask[idx[i * 256 + t]] = (unsigned char)0;
    __syncthreads();

    // 3) masked copy of this block's 4096 float4
    const int img_base = b * PER_IMG4;
    int local = blk * CHUNK4 + t;              // image-local float4 index
#pragma unroll 4
    for (int i = 0; i < ITERS; ++i) {
        int l  = local + i * 256;
        int y  = l / PER_ROW4;
        int x4 = l - y * PER_ROW4;
        int px = x4 / 6;                       // 6 float4 per patch along x
        int py = y >> 3;                       // 8 rows per patch
        unsigned char m = smask[(py << 6) + px];
        float4 v = make_float4(0.f, 0.f, 0.f, 0.f);
        if (m) v = in[img_base + l];           // exec-masked load
        out[img_base + l] = v;
    }
}

extern "C" void kernel_launch(void* const* d_in, const int* in_sizes, int n_in,
                              void* d_out, int out_size, void* d_ws, size_t ws_size,
                              hipStream_t stream) {
    const float* images       = (const float*)d_in[0];
    const int*   mask_indices = (const int*)d_in[1];
    float*       out          = (float*)d_out;

    rm_fused<<<BATCH * BLOCKS_PER_IMG, 256, 0, stream>>>(
        (const float4*)images, (float4*)out, mask_indices);
}